// Round 13
// baseline (440.917 us; speedup 1.0000x reference)
//
#include <hip/hip_runtime.h>
#include <hip/hip_bf16.h>

#define B_ 8
#define N_ 4096
#define D_ 512
#define BM 64
#define BK 32
#define NTH 512
#define NT (N_ / BK)

typedef __attribute__((ext_vector_type(8))) short bf16x8;
typedef __attribute__((ext_vector_type(4))) float f32x4;
typedef __attribute__((ext_vector_type(16))) float f32x16;

__device__ __forceinline__ short f2bs(float x) {
  union { __hip_bfloat16 h; short s; } u;
  u.h = __float2bfloat16(x);
  return u.s;
}

__device__ __forceinline__ void gld16(const void* g, void* l) {
  __builtin_amdgcn_global_load_lds((const __attribute__((address_space(1))) void*)g,
                                   (__attribute__((address_space(3))) void*)l, 16, 0, 0);
}

// ---------------- kernel 1: rn[b*N+n] = 1/||tgt[b,n,:]|| ----------------
__global__ void __launch_bounds__(256) rnorm_kernel(const float* __restrict__ tgt,
                                                    float* __restrict__ rn) {
  int row  = blockIdx.x * 4 + (threadIdx.x >> 6);
  int lane = threadIdx.x & 63;
  const float* p = tgt + (size_t)row * D_ + lane * 8;
  float4 a = *(const float4*)p;
  float4 b = *(const float4*)(p + 4);
  float s = a.x*a.x + a.y*a.y + a.z*a.z + a.w*a.w
          + b.x*b.x + b.y*b.y + b.z*b.z + b.w*b.w;
  #pragma unroll
  for (int m = 32; m >= 1; m >>= 1) s += __shfl_xor(s, m, 64);
  if (lane == 0) rn[row] = rsqrtf(s);
}

// ---------------- kernel 2: prep granule-8 layouts ----------------
// Tbf2[b][d>>3][n][d&7] = bf16( tgt[b][n][d] * rn[b][n] )   (normalized)
// Vt2 [b][n>>3][d][n&7] = bf16( tgt[b][n][d] )              (raw)
__global__ void __launch_bounds__(256) prep_kernel(const float* __restrict__ tgt,
                                                   const float* __restrict__ rn,
                                                   ushort* __restrict__ Tbf2,
                                                   ushort* __restrict__ Vt2) {
  __shared__ ushort L[64][72];                  // raw bf16 tile, padded
  const int id = blockIdx.x;                    // 8b x 64nt x 8dt
  const int b = id >> 9, nt = (id >> 3) & 63, dt = id & 7;
  const int n0 = nt * 64, d0 = dt * 64;
  const int t = threadIdx.x;
  const float* Tg  = tgt + ((size_t)b * N_ + n0) * D_ + d0;
  const float* rnb = rn + b * N_ + n0;
  ushort* T2 = Tbf2 + (size_t)b * N_ * D_;
  ushort* V2 = Vt2  + (size_t)b * N_ * D_;

  const int r = t >> 3, g = t & 7;              // row-half, d-granule
  #pragma unroll
  for (int p = 0; p < 2; ++p) {
    int row = p * 32 + r;
    const float* src = Tg + (size_t)row * D_ + g * 8;
    float4 f0 = *(const float4*)src;
    float4 f1 = *(const float4*)(src + 4);
    float sc = rnb[row];
    bf16x8 nv;
    nv[0]=f2bs(f0.x*sc); nv[1]=f2bs(f0.y*sc); nv[2]=f2bs(f0.z*sc); nv[3]=f2bs(f0.w*sc);
    nv[4]=f2bs(f1.x*sc); nv[5]=f2bs(f1.y*sc); nv[6]=f2bs(f1.z*sc); nv[7]=f2bs(f1.w*sc);
    *(bf16x8*)(T2 + ((size_t)(d0/8 + g) * N_ + n0 + row) * 8) = nv;
    bf16x8 rv;
    rv[0]=f2bs(f0.x); rv[1]=f2bs(f0.y); rv[2]=f2bs(f0.z); rv[3]=f2bs(f0.w);
    rv[4]=f2bs(f1.x); rv[5]=f2bs(f1.y); rv[6]=f2bs(f1.z); rv[7]=f2bs(f1.w);
    #pragma unroll
    for (int e = 0; e < 8; ++e) L[row][g*8 + e] = (ushort)rv[e];
  }
  __syncthreads();
  #pragma unroll
  for (int p = 0; p < 2; ++p) {
    int task = p * 256 + t;
    int ng = task >> 6, dd = task & 63;
    bf16x8 v;
    #pragma unroll
    for (int j = 0; j < 8; ++j) v[j] = (short)L[ng*8 + j][dd];
    *(bf16x8*)(V2 + ((size_t)(n0/8 + ng) * D_ + d0 + dd) * 8) = v;
  }
}

// ---------------- kernel 3: fused  out = tanh(Xn Xn^T) * tgt ----------------
// Tile-level software pipeline: each iteration runs S(t+1) and PV(t) as ONE
// merged phase (independent MFMA chains + LDS streams -> in-wave ILP), then
// tanh -> Pl[(t+1)&1], ONE __syncthreads. BK=32; KV/VT/Pl all double-buffered
// (136 KB). KV staged 2 tiles ahead, VT 1 tile ahead -> barrier drains free.
__global__ void __launch_bounds__(NTH, 2) fused_kernel(const ushort* __restrict__ Tbf2,
                                                       const ushort* __restrict__ Vt2,
                                                       float* __restrict__ out) {
  __shared__ __align__(16) ushort KVs[2][64 * BK * 8];       // [d/8=64][m32][8] 2x32 KB
  __shared__ __align__(16) ushort VTs[2][4 * D_ * 8];        // [m/8=4][d512][8] 2x32 KB
  __shared__ __align__(16) ushort Pls[2][4 * BM * 8];        // [m/8=4][q64][8]  2x 4 KB

  const int id = blockIdx.x;             // 512 blocks
  const int b  = id & 7;                 // batch -> XCD round-robin
  const int q0 = (id >> 3) * BM;

  const int lane = threadIdx.x & 63;
  const int w    = threadIdx.x >> 6;

  const ushort* Tb2 = Tbf2 + (size_t)b * N_ * D_;  // [d/8][n][8] normalized
  const ushort* Vb2 = Vt2  + (size_t)b * N_ * D_;  // [n/8][d][8] raw

  // ---- S mapping: wave -> q rows [qG*16,+16), m cols [mG*16,+16)
  const int qG = w >> 1;                 // 0..3
  const int mG = w & 1;                  // 0..1

  // Q fragments: 16 rows x 512 d = 64 VGPR
  bf16x8 qf[16];
  {
    const int row = q0 + qG * 16 + (lane & 15);
    #pragma unroll
    for (int kk = 0; kk < 16; ++kk)
      qf[kk] = *(const bf16x8*)(Tb2 + ((size_t)(kk * 4 + (lane >> 4)) * N_ + row) * 8);
  }

  f32x16 acc[2][2] = {};                 // [qt][dt]: wave tile 64q x 64d (d = [w*64,+64))

  // ---- hoisted LDS bases
  const int kvo = (lane >> 4) * 256 + (mG * 16 + (lane & 15)) * 8;
  const ushort* kvB0 = &KVs[0][kvo];
  const ushort* kvB1 = &KVs[1][kvo];
  const int pao = (lane >> 5) * 512 + (lane & 31) * 8;
  const ushort* pa0 = &Pls[0][pao];
  const ushort* pa1 = &Pls[1][pao];
  const int vbo = (lane >> 5) * 4096 + (w * 64 + (lane & 31)) * 8;
  const ushort* vb0 = &VTs[0][vbo];
  const ushort* vb1 = &VTs[1][vbo];
  const int mloc = mG * 16 + (lane & 15);
  const int plo = (mloc >> 3) * 512 + (qG * 16 + (lane >> 4) * 4) * 8 + (mloc & 7);
  ushort* plw0 = &Pls[0][plo];
  ushort* plw1 = &Pls[1][plo];

  // ---- staging helpers (4 gld16 per wave each)
  // KV tile mt -> KVs[buf]: chunk c = w*4+i covers granules 2c,2c+1
  // (per-lane global: g = 2c + (lane>>5), m-row = lane&31; LDS linear)
  auto STAGE_KV = [&](int mt, int buf) {
    #pragma unroll
    for (int i = 0; i < 4; ++i) {
      int c = w * 4 + i;
      const ushort* src = Tb2 + ((size_t)(2 * c + (lane >> 5)) * N_
                                 + mt * BK + (lane & 31)) * 8;
      gld16(src, &KVs[buf][c * 512]);
    }
  };
  // VT tile mt -> VTs[buf]: chunk c = w*4+i: mg = c>>3, dseg = c&7 (1KB contiguous)
  auto STAGE_VT = [&](int mt, int buf) {
    #pragma unroll
    for (int i = 0; i < 4; ++i) {
      int c = w * 4 + i;
      const ushort* src = Vb2 + ((size_t)(mt * 4 + (c >> 3)) * D_
                                 + (c & 7) * 64 + lane) * 8;
      gld16(src, &VTs[buf][(c >> 3) * 4096 + (c & 7) * 512]);
    }
  };

  // ---- S(t) into Pl[t&1] (16 MFMA, parity-split chains), t's KV buf given
  auto SPHASE = [&](const ushort* kvB, ushort* plw) {
    f32x4 se = {}, so = {};
    #pragma unroll
    for (int kk = 0; kk < 16; kk += 2) {
      bf16x8 b0 = *(const bf16x8*)(kvB + kk * 1024);
      bf16x8 b1 = *(const bf16x8*)(kvB + kk * 1024 + 1024);
      se = __builtin_amdgcn_mfma_f32_16x16x32_bf16(qf[kk],     b0, se, 0, 0, 0);
      so = __builtin_amdgcn_mfma_f32_16x16x32_bf16(qf[kk + 1], b1, so, 0, 0, 0);
    }
    #pragma unroll
    for (int j = 0; j < 4; ++j) {
      float s = se[j] + so[j];
      float e = __builtin_amdgcn_exp2f(s * 2.885390082f);   // e^(2s)
      float tn = 1.0f - 2.0f * __builtin_amdgcn_rcpf(e + 1.0f);
      plw[j * 8] = (ushort)f2bs(tn);
    }
  };

  // ---- PV(t): 8 MFMA-32x32 from Pl[t&1] + VTs[t&1]
  auto PVPHASE = [&](const ushort* pa, const ushort* vb) {
    #pragma unroll
    for (int ks = 0; ks < 2; ++ks) {
      bf16x8 a0 = *(const bf16x8*)(pa + ks * 1024);
      bf16x8 a1 = *(const bf16x8*)(pa + ks * 1024 + 256);
      bf16x8 v0 = *(const bf16x8*)(vb + ks * 8192);
      bf16x8 v1 = *(const bf16x8*)(vb + ks * 8192 + 256);
      acc[0][0] = __builtin_amdgcn_mfma_f32_32x32x16_bf16(a0, v0, acc[0][0], 0, 0, 0);
      acc[0][1] = __builtin_amdgcn_mfma_f32_32x32x16_bf16(a0, v1, acc[0][1], 0, 0, 0);
      acc[1][0] = __builtin_amdgcn_mfma_f32_32x32x16_bf16(a1, v0, acc[1][0], 0, 0, 0);
      acc[1][1] = __builtin_amdgcn_mfma_f32_32x32x16_bf16(a1, v1, acc[1][1], 0, 0, 0);
    }
  };

  // ---- prologue: KV(0)->buf0, KV(1)->buf1, VT(0)->buf0; S(0)->Pl[0]
  STAGE_KV(0, 0);
  STAGE_KV(1, 1);
  STAGE_VT(0, 0);
  __syncthreads();                       // drains all prologue staging
  SPHASE(kvB0, plw0);
  __syncthreads();                       // Pl[0] visible

  // ---- main loop: iteration t runs { stage KV(t+2), VT(t+1), S(t+1) || PV(t) }
  for (int t = 0; t < NT; ++t) {
    const bool haveS = (t + 1 < NT);
    if (t + 2 < NT) STAGE_KV(t + 2, t & 1);
    if (haveS)      STAGE_VT(t + 1, (t + 1) & 1);

    const ushort* kvB = ((t + 1) & 1) ? kvB1 : kvB0;
    const ushort* pa  = (t & 1) ? pa1 : pa0;
    const ushort* vb  = (t & 1) ? vb1 : vb0;
    ushort* plw       = ((t + 1) & 1) ? plw1 : plw0;

    __builtin_amdgcn_s_setprio(1);
    if (haveS) {
      // merged phase: S(t+1) and PV(t) interleaved (independent chains)
      f32x4 se = {}, so = {};
      #pragma unroll
      for (int h = 0; h < 2; ++h) {
        #pragma unroll
        for (int kk = h * 8; kk < h * 8 + 8; kk += 2) {
          bf16x8 b0 = *(const bf16x8*)(kvB + kk * 1024);
          bf16x8 b1 = *(const bf16x8*)(kvB + kk * 1024 + 1024);
          se = __builtin_amdgcn_mfma_f32_16x16x32_bf16(qf[kk],     b0, se, 0, 0, 0);
          so = __builtin_amdgcn_mfma_f32_16x16x32_bf16(qf[kk + 1], b1, so, 0, 0, 0);
        }
        // one PV k-slice between S halves
        {
          int ks = h;
          bf16x8 a0 = *(const bf16x8*)(pa + ks * 1024);
          bf16x8 a1 = *(const bf16x8*)(pa + ks * 1024 + 256);
          bf16x8 v0 = *(const bf16x8*)(vb + ks * 8192);
          bf16x8 v1 = *(const bf16x8*)(vb + ks * 8192 + 256);
          acc[0][0] = __builtin_amdgcn_mfma_f32_32x32x16_bf16(a0, v0, acc[0][0], 0, 0, 0);
          acc[0][1] = __builtin_amdgcn_mfma_f32_32x32x16_bf16(a0, v1, acc[0][1], 0, 0, 0);
          acc[1][0] = __builtin_amdgcn_mfma_f32_32x32x16_bf16(a1, v0, acc[1][0], 0, 0, 0);
          acc[1][1] = __builtin_amdgcn_mfma_f32_32x32x16_bf16(a1, v1, acc[1][1], 0, 0, 0);
        }
      }
      #pragma unroll
      for (int j = 0; j < 4; ++j) {
        float s = se[j] + so[j];
        float e = __builtin_amdgcn_exp2f(s * 2.885390082f);
        float tn = 1.0f - 2.0f * __builtin_amdgcn_rcpf(e + 1.0f);
        plw[j * 8] = (ushort)f2bs(tn);
      }
    } else {
      PVPHASE(pa, vb);                   // last tile: PV only
    }
    __builtin_amdgcn_s_setprio(0);
    __syncthreads();                     // one barrier per tile (drains are free)
  }

  // ---- write out [64 x 512] fp32; C/D 32x32: row=(reg&3)+8*(reg>>2)+4*(lane>>5)
  {
    float* op = out + (size_t)b * N_ * D_ + (size_t)q0 * D_;
    #pragma unroll
    for (int qt = 0; qt < 2; ++qt)
      #pragma unroll
      for (int dt = 0; dt < 2; ++dt) {
        int d = w * 64 + dt * 32 + (lane & 31);
        #pragma unroll
        for (int reg = 0; reg < 16; ++reg) {
          int row = qt * 32 + (reg & 3) + 8 * (reg >> 2) + 4 * (lane >> 5);
          op[(size_t)row * D_ + d] = acc[qt][dt][reg];
        }
      }
  }
}

extern "C" void kernel_launch(void* const* d_in, const int* in_sizes, int n_in,
                              void* d_out, int out_size, void* d_ws, size_t ws_size,
                              hipStream_t stream) {
  const float* tgt = (const float*)d_in[0];
  float* outp = (float*)d_out;

  float*  rn   = (float*)d_ws;                                    // 128 KB
  ushort* Tbf2 = (ushort*)((char*)d_ws + (1 << 17));              // 32 MB
  ushort* Vt2  = Tbf2 + (size_t)B_ * N_ * D_;                     // 32 MB

  rnorm_kernel<<<dim3((B_ * N_) / 4), dim3(256), 0, stream>>>(tgt, rn);
  prep_kernel<<<dim3(B_ * 64 * 8), dim3(256), 0, stream>>>(tgt, rn, Tbf2, Vt2);
  fused_kernel<<<dim3(B_ * (N_ / BM)), dim3(NTH), 0, stream>>>(Tbf2, Vt2, outp);
}

// Round 14
// 339.124 us; speedup vs baseline: 1.3002x; 1.3002x over previous
//
#include <hip/hip_runtime.h>
#include <hip/hip_bf16.h>

#define B_ 8
#define N_ 4096
#define D_ 512
#define BM 64
#define BK 64
#define NTH 512
#define NT (N_ / BK)

typedef __attribute__((ext_vector_type(8))) short bf16x8;
typedef __attribute__((ext_vector_type(4))) float f32x4;
typedef __attribute__((ext_vector_type(16))) float f32x16;

__device__ __forceinline__ short f2bs(float x) {
  union { __hip_bfloat16 h; short s; } u;
  u.h = __float2bfloat16(x);
  return u.s;
}

__device__ __forceinline__ void gld16(const void* g, void* l) {
  __builtin_amdgcn_global_load_lds((const __attribute__((address_space(1))) void*)g,
                                   (__attribute__((address_space(3))) void*)l, 16, 0, 0);
}

// ---------------- kernel 1: fused rnorm + prep (one pass over tgt) ----------
// Tbf2[b][d>>3][n][d&7] = bf16( tgt[b][n][d] / ||tgt[b,n,:]|| )   (normalized)
// Vt2 [b][n>>3][d][n&7] = bf16( tgt[b][n][d] )                    (raw)
// Block = 32 full rows (8 lanes per row); row norm via in-register
// sum-of-squares + 8-lane shfl_xor reduce; no separate rnorm kernel, no rn buf.
__global__ void __launch_bounds__(256) prep_kernel(const float* __restrict__ tgt,
                                                   ushort* __restrict__ Tbf2,
                                                   ushort* __restrict__ Vt2) {
  __shared__ ushort L[32][520];                 // raw bf16 rows, padded stride
  const int id = blockIdx.x;                    // 8b x 128 row-groups
  const int b = id >> 7, rg = id & 127;
  const int n0 = rg * 32;
  const int t = threadIdx.x;
  const int r = t >> 3, q = t & 7;              // row 0..31, lane-in-row 0..7

  const float* src = tgt + ((size_t)b * N_ + n0 + r) * D_;
  ushort* T2 = Tbf2 + (size_t)b * N_ * D_;
  ushort* V2 = Vt2  + (size_t)b * N_ * D_;

  // read the full row slice (8 d-granules of 8), accumulate sum of squares
  float4 f[8][2];
  float ss = 0.0f;
  #pragma unroll
  for (int c = 0; c < 8; ++c) {
    const float* p = src + (c * 8 + q) * 8;
    f[c][0] = *(const float4*)p;
    f[c][1] = *(const float4*)(p + 4);
    ss += f[c][0].x * f[c][0].x + f[c][0].y * f[c][0].y
        + f[c][0].z * f[c][0].z + f[c][0].w * f[c][0].w
        + f[c][1].x * f[c][1].x + f[c][1].y * f[c][1].y
        + f[c][1].z * f[c][1].z + f[c][1].w * f[c][1].w;
  }
  // 8-lane reduce (lanes of one row are contiguous in the wave)
  ss += __shfl_xor(ss, 1, 64);
  ss += __shfl_xor(ss, 2, 64);
  ss += __shfl_xor(ss, 4, 64);
  const float rs = rsqrtf(ss);

  #pragma unroll
  for (int c = 0; c < 8; ++c) {
    const int g2 = c * 8 + q;                   // global d-granule
    bf16x8 nv, rv;
    nv[0]=f2bs(f[c][0].x*rs); nv[1]=f2bs(f[c][0].y*rs);
    nv[2]=f2bs(f[c][0].z*rs); nv[3]=f2bs(f[c][0].w*rs);
    nv[4]=f2bs(f[c][1].x*rs); nv[5]=f2bs(f[c][1].y*rs);
    nv[6]=f2bs(f[c][1].z*rs); nv[7]=f2bs(f[c][1].w*rs);
    *(bf16x8*)(T2 + ((size_t)g2 * N_ + n0 + r) * 8) = nv;
    rv[0]=f2bs(f[c][0].x); rv[1]=f2bs(f[c][0].y);
    rv[2]=f2bs(f[c][0].z); rv[3]=f2bs(f[c][0].w);
    rv[4]=f2bs(f[c][1].x); rv[5]=f2bs(f[c][1].y);
    rv[6]=f2bs(f[c][1].z); rv[7]=f2bs(f[c][1].w);
    #pragma unroll
    for (int e = 0; e < 8; ++e) L[r][g2 * 8 + e] = (ushort)rv[e];
  }
  __syncthreads();

  // transpose -> Vt2: task tau covers (ng = tau>>9, d = tau&511)
  #pragma unroll
  for (int c2 = 0; c2 < 8; ++c2) {
    int tau = c2 * 256 + t;
    int ng = tau >> 9, d = tau & 511;
    bf16x8 v;
    #pragma unroll
    for (int j = 0; j < 8; ++j) v[j] = (short)L[ng * 8 + j][d];
    *(bf16x8*)(V2 + ((size_t)(n0 / 8 + ng) * D_ + d) * 8) = v;
  }
}

// ---------------- kernel 2: fused  out = tanh(Xn Xn^T) * tgt ----------------
// Byte-identical to the r7 best point (348.6 us): r4 skeleton, hoisted LDS
// bases + imm offsets, hoisted staging pointers, setprio around MFMA clusters.
// S: 16x16x32 grid 4q x 2m (qf[16], 64 VGPR). PV: 32x32x16, grid 1q x 8d.
__global__ void __launch_bounds__(NTH, 2) fused_kernel(const ushort* __restrict__ Tbf2,
                                                       const ushort* __restrict__ Vt2,
                                                       float* __restrict__ out) {
  __shared__ __align__(16) ushort KV[BK * D_];   // [d/8][m][8] normalized  64 KB
  __shared__ __align__(16) ushort VT[BK * D_];   // [m/8][d][8] raw         64 KB
  __shared__ __align__(16) ushort Pl[BM * BK];   // [m/8][q][8]              8 KB

  const int id = blockIdx.x;             // 512 blocks
  const int b  = id & 7;                 // batch -> XCD round-robin
  const int q0 = (id >> 3) * BM;

  const int lane = threadIdx.x & 63;
  const int w    = threadIdx.x >> 6;

  const ushort* Tb2 = Tbf2 + (size_t)b * N_ * D_;  // [d/8][n][8] normalized
  const ushort* Vb2 = Vt2  + (size_t)b * N_ * D_;  // [n/8][d][8] raw

  // ---- S mapping: wave -> q rows [qG*16,+16), m cols [mG*32,+32)
  const int qG = w >> 1;                 // 0..3
  const int mG = w & 1;                  // 0..1

  // Q fragments: 16 rows x 512 d = 64 VGPR
  bf16x8 qf[16];
  {
    const int row = q0 + qG * 16 + (lane & 15);
    #pragma unroll
    for (int kk = 0; kk < 16; ++kk) {
      int g = kk * 4 + (lane >> 4);
      qf[kk] = *(const bf16x8*)(Tb2 + ((size_t)g * N_ + row) * 8);
    }
  }

  f32x16 acc[2][2] = {};                 // wave tile 64q x 64d (d-cols [w*64,+64))

  // ---- hoisted LDS read bases (ushort indices; all loop offsets are consts)
  const ushort* kvrd = &KV[(lane >> 4) * 512 + (mG * 32 + (lane & 15)) * 8];
  const ushort* pard = &Pl[(lane >> 5) * 512 + (lane & 31) * 8];
  const ushort* vbrd = &VT[(lane >> 5) * 4096 + (w * 64 + (lane & 31)) * 8];
  ushort*       plwr = &Pl[((mG * 32 + (lane & 15)) >> 3) * 512
                           + (qG * 16 + (lane >> 4) * 4) * 8
                           + ((lane & 15) & 7)];

  // ---- hoisted staging pointers (advance by constants each tile)
  const ushort* kvsrc = Tb2 + (size_t)(w * 8) * N_ * 8 + (size_t)BK * 8 + lane * 8;
  const ushort* vtsrc = Vb2 + (size_t)(8 + w) * D_ * 8 + lane * 8;

  // prologue: stage tile 0
  #pragma unroll
  for (int i = 0; i < 8; ++i)
    gld16(Tb2 + ((size_t)(w * 8 + i) * N_) * 8 + lane * 8, &KV[(w * 8 + i) * 512]);
  #pragma unroll
  for (int i = 0; i < 8; ++i)
    gld16(Vb2 + (size_t)w * D_ * 8 + i * 512 + lane * 8, &VT[w * 4096 + i * 512]);
  __syncthreads();

  for (int t = 0; t < NT; ++t) {
    // ---- S = Qn * Kn^T : 32 reads (imm offsets), 32 MFMA-16x16 per wave
    f32x4 sacc[2] = {};
    __builtin_amdgcn_s_setprio(1);
    #pragma unroll
    for (int kk = 0; kk < 16; ++kk) {
      bf16x8 b0 = *(const bf16x8*)(kvrd + kk * 2048);
      bf16x8 b1 = *(const bf16x8*)(kvrd + kk * 2048 + 128);
      sacc[0] = __builtin_amdgcn_mfma_f32_16x16x32_bf16(qf[kk], b0, sacc[0], 0, 0, 0);
      sacc[1] = __builtin_amdgcn_mfma_f32_16x16x32_bf16(qf[kk], b1, sacc[1], 0, 0, 0);
    }
    __builtin_amdgcn_s_setprio(0);

    // ---- tanh -> Pl ([m/8][q][8])
    #pragma unroll
    for (int f = 0; f < 2; ++f)
      #pragma unroll
      for (int j = 0; j < 4; ++j) {
        float e = __builtin_amdgcn_exp2f(sacc[f][j] * 2.885390082f);  // e^(2s)
        float tn = 1.0f - 2.0f * __builtin_amdgcn_rcpf(e + 1.0f);
        plwr[f * 1024 + j * 8] = (ushort)f2bs(tn);
      }
    __syncthreads();                     // bar1: Pl visible; VT(t) drained

    if (t < NT - 1) {                    // stage KV(t+1), lands during PV
      #pragma unroll
      for (int i = 0; i < 8; ++i)
        gld16(kvsrc + (size_t)i * N_ * 8, &KV[(w * 8 + i) * 512]);
      kvsrc += BK * 8;                   // +1 KB
    }

    // ---- out += P * V : 16 reads (imm offsets), 16 MFMA-32x32 per wave
    __builtin_amdgcn_s_setprio(1);
    #pragma unroll
    for (int ks = 0; ks < 4; ++ks) {
      bf16x8 pa0 = *(const bf16x8*)(pard + ks * 1024);
      bf16x8 pa1 = *(const bf16x8*)(pard + ks * 1024 + 256);
      bf16x8 vb0 = *(const bf16x8*)(vbrd + ks * 8192);
      bf16x8 vb1 = *(const bf16x8*)(vbrd + ks * 8192 + 256);
      acc[0][0] = __builtin_amdgcn_mfma_f32_32x32x16_bf16(pa0, vb0, acc[0][0], 0, 0, 0);
      acc[0][1] = __builtin_amdgcn_mfma_f32_32x32x16_bf16(pa0, vb1, acc[0][1], 0, 0, 0);
      acc[1][0] = __builtin_amdgcn_mfma_f32_32x32x16_bf16(pa1, vb0, acc[1][0], 0, 0, 0);
      acc[1][1] = __builtin_amdgcn_mfma_f32_32x32x16_bf16(pa1, vb1, acc[1][1], 0, 0, 0);
    }
    __builtin_amdgcn_s_setprio(0);
    __syncthreads();                     // bar2: PV done; KV(t+1) drained; VT free

    if (t < NT - 1) {                    // stage VT(t+1), lands during S(t+1)
      #pragma unroll
      for (int i = 0; i < 8; ++i)
        gld16(vtsrc + i * 512, &VT[w * 4096 + i * 512]);
      vtsrc += 8 * D_ * 8;               // +64 KB
    }
  }

  // ---- write out [64 x 512] fp32; C/D 32x32: row=(reg&3)+8*(reg>>2)+4*(lane>>5)
  {
    float* op = out + (size_t)b * N_ * D_ + (size_t)q0 * D_;
    #pragma unroll
    for (int qs = 0; qs < 2; ++qs)
      #pragma unroll
      for (int ds = 0; ds < 2; ++ds) {
        int d = w * 64 + ds * 32 + (lane & 31);
        #pragma unroll
        for (int reg = 0; reg < 16; ++reg) {
          int row = qs * 32 + (reg & 3) + 8 * (reg >> 2) + 4 * (lane >> 5);
          op[(size_t)row * D_ + d] = acc[qs][ds][reg];
        }
      }
  }
}

extern "C" void kernel_launch(void* const* d_in, const int* in_sizes, int n_in,
                              void* d_out, int out_size, void* d_ws, size_t ws_size,
                              hipStream_t stream) {
  const float* tgt = (const float*)d_in[0];
  float* outp = (float*)d_out;

  ushort* Tbf2 = (ushort*)d_ws;                                   // 32 MB
  ushort* Vt2  = Tbf2 + (size_t)B_ * N_ * D_;                     // 32 MB

  prep_kernel<<<dim3(B_ * 128), dim3(256), 0, stream>>>(tgt, Tbf2, Vt2);
  fused_kernel<<<dim3(B_ * (N_ / BM)), dim3(NTH), 0, stream>>>(Tbf2, Vt2, outp);
}